// Round 5
// baseline (1664.995 us; speedup 1.0000x reference)
//
#include <hip/hip_runtime.h>
#include <hip/hip_bf16.h>
#include <math.h>

// Problem constants
#define HDIM 1024      // hidden
#define TOK 2048       // B*S tokens
#define NHEAD 8
#define KD 128
#define NKEY 256
#define KSEL 8
#define NQ 2048        // 2*NH*KD
#define BN_EPS 1e-5f

// ---------------- K1: BatchNorm partial sums ----------------
__global__ __launch_bounds__(256) void bn_partial_k(const float* __restrict__ x,
                                                    float* __restrict__ psum,
                                                    float* __restrict__ psq) {
    int b = blockIdx.x;
    int t = threadIdx.x;
    float s[4] = {0.f, 0.f, 0.f, 0.f};
    float s2[4] = {0.f, 0.f, 0.f, 0.f};
    int r0 = b * 32;
    for (int r = 0; r < 32; ++r) {
        const float* row = x + (size_t)(r0 + r) * HDIM;
#pragma unroll
        for (int j = 0; j < 4; ++j) {
            float v = row[t + j * 256];
            s[j] += v;
            s2[j] += v * v;
        }
    }
#pragma unroll
    for (int j = 0; j < 4; ++j) {
        psum[b * HDIM + t + j * 256] = s[j];
        psq[b * HDIM + t + j * 256] = s2[j];
    }
}

// ---------------- K2: finalize scale/shift ----------------
__global__ __launch_bounds__(256) void bn_final_k(const float* __restrict__ psum,
                                                  const float* __restrict__ psq,
                                                  const float* __restrict__ gamma,
                                                  const float* __restrict__ beta,
                                                  float* __restrict__ scale,
                                                  float* __restrict__ shift) {
    int c = blockIdx.x * 256 + threadIdx.x;  // 0..1023
    float s = 0.f, s2 = 0.f;
    for (int b = 0; b < 64; ++b) {
        s += psum[b * HDIM + c];
        s2 += psq[b * HDIM + c];
    }
    float mean = s * (1.0f / TOK);
    float var = s2 * (1.0f / TOK) - mean * mean;
    float sc = gamma[c] * rsqrtf(var + BN_EPS);
    scale[c] = sc;
    shift[c] = beta[c] - mean * sc;
}

// ---------------- K3-new: 16x8 micro-tile fp32 GEMM (LDS-instruction optimized) ----
// 256 threads, tile 256(M)x128(N), BK=16, micro-tile 16x8, double-buffered LDS.
// MODE 0: A = x (norm on the fly), B = w_q. grid (8,16,2): z = K-split half.
//         C plane z at C + z*4194304 (2048x2048 each).
// MODE 1: A = qp0 (+ qp1 summed), B = keys slice. grid (8,2,16): z = (p,h).
template <int MODE>
__global__ __launch_bounds__(256, 2) void gemm2_k(const float* __restrict__ A,
                                                  const float* __restrict__ A2,
                                                  const float* __restrict__ B,
                                                  float* __restrict__ C,
                                                  const float* __restrict__ scale,
                                                  const float* __restrict__ shift) {
    __shared__ __align__(16) float As[2][16][256];
    __shared__ __align__(16) float Bs[2][16][128];

    const int tid = threadIdx.x;
    const int m0 = blockIdx.x * 256;
    const int n0 = blockIdx.y * 128;

    const float* Ab;
    const float* A2b = nullptr;
    const float* Bb;
    float* Cb;
    int kb, nsteps, LDA, LDB, LDC;
    if (MODE == 0) {
        LDA = 1024; LDB = 1024; LDC = 2048;
        kb = blockIdx.z * 512;
        nsteps = 32;
        Ab = A;
        Bb = B;
        Cb = C + (size_t)blockIdx.z * 4194304;
    } else {
        LDA = 2048; LDB = 256; LDC = 4096;
        kb = 0;
        nsteps = 8;
        int z = blockIdx.z;
        int p = z >> 3, h = z & 7;
        Ab = A + p * 1024 + h * 128;
        A2b = A2 + p * 1024 + h * 128;
        Bb = B + h * 65536 + p * 128;
        Cb = C + p * 2048 + h * 256;
    }

    // staging pointers: A row (m0+tid), 16 cols; B row n0+(tid&127), 8 cols
    const float* ap = Ab + (size_t)(m0 + tid) * LDA + kb;
    const float* ap2 = (MODE == 1) ? (A2b + (size_t)(m0 + tid) * LDA + kb) : nullptr;
    const int brow = tid & 127;
    const int bc8 = (tid >> 7) * 8;
    const float* bp = Bb + (size_t)(n0 + brow) * LDB + kb + bc8;

    float acc[16][8];
#pragma unroll
    for (int i = 0; i < 16; ++i)
#pragma unroll
        for (int j = 0; j < 8; ++j) acc[i][j] = 0.f;

    const int tm = tid >> 4;   // 0..15 -> rows tm*16..+15
    const int tn = tid & 15;   // 0..15 -> cols tn*8..+7

    // ---- stage step 0 into buf 0 ----
    {
        float4 av[4];
#pragma unroll
        for (int j = 0; j < 4; ++j) {
            av[j] = *(const float4*)(ap + j * 4);
            if (MODE == 0) {
                float4 s4 = *(const float4*)(scale + kb + j * 4);
                float4 h4 = *(const float4*)(shift + kb + j * 4);
                av[j].x = fmaf(av[j].x, s4.x, h4.x);
                av[j].y = fmaf(av[j].y, s4.y, h4.y);
                av[j].z = fmaf(av[j].z, s4.z, h4.z);
                av[j].w = fmaf(av[j].w, s4.w, h4.w);
            } else {
                float4 a2 = *(const float4*)(ap2 + j * 4);
                av[j].x += a2.x; av[j].y += a2.y; av[j].z += a2.z; av[j].w += a2.w;
            }
        }
        float4 bv[2];
        bv[0] = *(const float4*)(bp);
        bv[1] = *(const float4*)(bp + 4);
#pragma unroll
        for (int j = 0; j < 4; ++j) {
            As[0][j * 4 + 0][tid] = av[j].x;
            As[0][j * 4 + 1][tid] = av[j].y;
            As[0][j * 4 + 2][tid] = av[j].z;
            As[0][j * 4 + 3][tid] = av[j].w;
        }
#pragma unroll
        for (int j = 0; j < 2; ++j) {
            Bs[0][bc8 + j * 4 + 0][brow] = bv[j].x;
            Bs[0][bc8 + j * 4 + 1][brow] = bv[j].y;
            Bs[0][bc8 + j * 4 + 2][brow] = bv[j].z;
            Bs[0][bc8 + j * 4 + 3][brow] = bv[j].w;
        }
    }
    __syncthreads();

    for (int s = 0; s < nsteps; ++s) {
        const int buf = s & 1;
        const bool more = (s + 1) < nsteps;
        float4 av[4], bv[2];
        if (more) {
            const int kt = (s + 1) * 16;
#pragma unroll
            for (int j = 0; j < 4; ++j) {
                av[j] = *(const float4*)(ap + kt + j * 4);
                if (MODE == 0) {
                    float4 s4 = *(const float4*)(scale + kb + kt + j * 4);
                    float4 h4 = *(const float4*)(shift + kb + kt + j * 4);
                    av[j].x = fmaf(av[j].x, s4.x, h4.x);
                    av[j].y = fmaf(av[j].y, s4.y, h4.y);
                    av[j].z = fmaf(av[j].z, s4.z, h4.z);
                    av[j].w = fmaf(av[j].w, s4.w, h4.w);
                } else {
                    float4 a2 = *(const float4*)(ap2 + kt + j * 4);
                    av[j].x += a2.x; av[j].y += a2.y; av[j].z += a2.z; av[j].w += a2.w;
                }
            }
            bv[0] = *(const float4*)(bp + kt);
            bv[1] = *(const float4*)(bp + kt + 4);
        }
#pragma unroll
        for (int kk = 0; kk < 16; ++kk) {
            float4 a0 = *(const float4*)&As[buf][kk][tm * 16];
            float4 a1 = *(const float4*)&As[buf][kk][tm * 16 + 4];
            float4 a2v = *(const float4*)&As[buf][kk][tm * 16 + 8];
            float4 a3 = *(const float4*)&As[buf][kk][tm * 16 + 12];
            float4 b0 = *(const float4*)&Bs[buf][kk][tn * 8];
            float4 b1 = *(const float4*)&Bs[buf][kk][tn * 8 + 4];
            float a[16] = {a0.x, a0.y, a0.z, a0.w, a1.x, a1.y, a1.z, a1.w,
                           a2v.x, a2v.y, a2v.z, a2v.w, a3.x, a3.y, a3.z, a3.w};
            float b[8] = {b0.x, b0.y, b0.z, b0.w, b1.x, b1.y, b1.z, b1.w};
#pragma unroll
            for (int i = 0; i < 16; ++i)
#pragma unroll
                for (int j = 0; j < 8; ++j) acc[i][j] = fmaf(a[i], b[j], acc[i][j]);
        }
        if (more) {
            const int nb = buf ^ 1;
#pragma unroll
            for (int j = 0; j < 4; ++j) {
                As[nb][j * 4 + 0][tid] = av[j].x;
                As[nb][j * 4 + 1][tid] = av[j].y;
                As[nb][j * 4 + 2][tid] = av[j].z;
                As[nb][j * 4 + 3][tid] = av[j].w;
            }
#pragma unroll
            for (int j = 0; j < 2; ++j) {
                Bs[nb][bc8 + j * 4 + 0][brow] = bv[j].x;
                Bs[nb][bc8 + j * 4 + 1][brow] = bv[j].y;
                Bs[nb][bc8 + j * 4 + 2][brow] = bv[j].z;
                Bs[nb][bc8 + j * 4 + 3][brow] = bv[j].w;
            }
            __syncthreads();
        }
    }

#pragma unroll
    for (int i = 0; i < 16; ++i) {
        float* crow = Cb + (size_t)(m0 + tm * 16 + i) * LDC + n0 + tn * 8;
        *(float4*)(crow) = make_float4(acc[i][0], acc[i][1], acc[i][2], acc[i][3]);
        *(float4*)(crow + 4) = make_float4(acc[i][4], acc[i][5], acc[i][6], acc[i][7]);
    }
}

// ---------------- K3-old (fallback if ws too small): 8x4 GEMM ----------------
template <int MODE>
__global__ __launch_bounds__(512) void gemm_k(const float* __restrict__ A,
                                              const float* __restrict__ Bm,
                                              float* __restrict__ C,
                                              const float* __restrict__ scale,
                                              const float* __restrict__ shift,
                                              int lda, int ldb, int ldc, int K) {
    __shared__ __align__(16) float As[2][16][128];
    __shared__ __align__(16) float Bs[2][16][128];
    const float* Ab = A;
    const float* Bb = Bm;
    float* Cb = C;
    if (MODE == 1) {
        int z = blockIdx.z;
        int p = z >> 3, h = z & 7;
        Ab += p * 1024 + h * 128;
        Bb += h * 65536 + p * 128;
        Cb += p * 2048 + h * 256;
    }
    const int m0 = blockIdx.x * 128;
    const int n0 = blockIdx.y * 128;
    const int tid = threadIdx.x;
    const int lr = tid >> 2;
    const int lc = (tid & 3) * 4;
    const int tm = tid >> 5;
    const int tn = tid & 31;

    float acc[8][4] = {};

    const float* arow = Ab + (size_t)(m0 + lr) * lda + lc;
    const float* brow = Bb + (size_t)(n0 + lr) * ldb + lc;

    {
        float4 av = *(const float4*)(arow);
        if (MODE == 0) {
            float4 s4 = *(const float4*)(scale + lc);
            float4 h4 = *(const float4*)(shift + lc);
            av.x = fmaf(av.x, s4.x, h4.x);
            av.y = fmaf(av.y, s4.y, h4.y);
            av.z = fmaf(av.z, s4.z, h4.z);
            av.w = fmaf(av.w, s4.w, h4.w);
        }
        float4 bv = *(const float4*)(brow);
        As[0][lc + 0][lr] = av.x;
        As[0][lc + 1][lr] = av.y;
        As[0][lc + 2][lr] = av.z;
        As[0][lc + 3][lr] = av.w;
        Bs[0][lc + 0][lr] = bv.x;
        Bs[0][lc + 1][lr] = bv.y;
        Bs[0][lc + 2][lr] = bv.z;
        Bs[0][lc + 3][lr] = bv.w;
    }
    __syncthreads();

    const int NS = K >> 4;
    for (int s = 0; s < NS; ++s) {
        const int buf = s & 1;
        float4 av, bv;
        const bool more = (s + 1) < NS;
        if (more) {
            int kt = (s + 1) << 4;
            av = *(const float4*)(arow + kt);
            if (MODE == 0) {
                float4 s4 = *(const float4*)(scale + kt + lc);
                float4 h4 = *(const float4*)(shift + kt + lc);
                av.x = fmaf(av.x, s4.x, h4.x);
                av.y = fmaf(av.y, s4.y, h4.y);
                av.z = fmaf(av.z, s4.z, h4.z);
                av.w = fmaf(av.w, s4.w, h4.w);
            }
            bv = *(const float4*)(brow + kt);
        }
#pragma unroll
        for (int kk = 0; kk < 16; ++kk) {
            float4 a0 = *(const float4*)&As[buf][kk][tm * 8];
            float4 a1 = *(const float4*)&As[buf][kk][tm * 8 + 4];
            float4 b0 = *(const float4*)&Bs[buf][kk][tn * 4];
            float a[8] = {a0.x, a0.y, a0.z, a0.w, a1.x, a1.y, a1.z, a1.w};
            float b[4] = {b0.x, b0.y, b0.z, b0.w};
#pragma unroll
            for (int i = 0; i < 8; ++i)
#pragma unroll
                for (int j = 0; j < 4; ++j) acc[i][j] = fmaf(a[i], b[j], acc[i][j]);
        }
        if (more) {
            const int nb = buf ^ 1;
            As[nb][lc + 0][lr] = av.x;
            As[nb][lc + 1][lr] = av.y;
            As[nb][lc + 2][lr] = av.z;
            As[nb][lc + 3][lr] = av.w;
            Bs[nb][lc + 0][lr] = bv.x;
            Bs[nb][lc + 1][lr] = bv.y;
            Bs[nb][lc + 2][lr] = bv.z;
            Bs[nb][lc + 3][lr] = bv.w;
            __syncthreads();
        }
    }
#pragma unroll
    for (int i = 0; i < 8; ++i) {
        float4 o = make_float4(acc[i][0], acc[i][1], acc[i][2], acc[i][3]);
        *(float4*)(Cb + (size_t)(m0 + tm * 8 + i) * ldc + n0 + tn * 4) = o;
    }
}

// ---------------- K4: top-k per (token, head) ----------------
__global__ __launch_bounds__(512) void topk_k(const float* __restrict__ sim,
                                              int* __restrict__ eidx,
                                              float* __restrict__ gates) {
    int t = blockIdx.x;
    int h = threadIdx.x >> 6;
    int lane = threadIdx.x & 63;
    const float* s0p = sim + (size_t)t * 4096 + h * 256;
    const float* s1p = s0p + 2048;
    float4 v0 = *(const float4*)(s0p + lane * 4);
    float4 v1 = *(const float4*)(s1p + lane * 4);
    float c0[4] = {v0.x, v0.y, v0.z, v0.w};
    float c1[4] = {v1.x, v1.y, v1.z, v1.w};

    float tv0[8], tv1[8];
    int ti0[8], ti1[8];

#pragma unroll
    for (int r = 0; r < 8; ++r) {
        float bv = c0[0];
        int bi = lane * 4;
#pragma unroll
        for (int j = 1; j < 4; ++j)
            if (c0[j] > bv) { bv = c0[j]; bi = lane * 4 + j; }
#pragma unroll
        for (int off = 1; off < 64; off <<= 1) {
            float ov = __shfl_xor(bv, off);
            int oi = __shfl_xor(bi, off);
            if (ov > bv || (ov == bv && oi < bi)) { bv = ov; bi = oi; }
        }
        tv0[r] = bv;
        ti0[r] = bi;
        if ((bi >> 2) == lane) {
            int jj = bi & 3;
#pragma unroll
            for (int q = 0; q < 4; ++q)
                if (q == jj) c0[q] = -INFINITY;
        }
    }
#pragma unroll
    for (int r = 0; r < 8; ++r) {
        float bv = c1[0];
        int bi = lane * 4;
#pragma unroll
        for (int j = 1; j < 4; ++j)
            if (c1[j] > bv) { bv = c1[j]; bi = lane * 4 + j; }
#pragma unroll
        for (int off = 1; off < 64; off <<= 1) {
            float ov = __shfl_xor(bv, off);
            int oi = __shfl_xor(bi, off);
            if (ov > bv || (ov == bv && oi < bi)) { bv = ov; bi = oi; }
        }
        tv1[r] = bv;
        ti1[r] = bi;
        if ((bi >> 2) == lane) {
            int jj = bi & 3;
#pragma unroll
            for (int q = 0; q < 4; ++q)
                if (q == jj) c1[q] = -INFINITY;
        }
    }

    int ii = lane >> 3, jj = lane & 7;
    float a = -INFINITY, b = -INFINITY;
#pragma unroll
    for (int r = 0; r < 8; ++r) {
        if (ii == r) a = tv0[r];
        if (jj == r) b = tv1[r];
    }
    float cv = a + b;
    int cpos = lane;

    int outbase = (t * NHEAD + h) * KSEL;
#pragma unroll
    for (int r = 0; r < 8; ++r) {
        float bv = cv;
        int bp = cpos;
#pragma unroll
        for (int off = 1; off < 64; off <<= 1) {
            float ov = __shfl_xor(bv, off);
            int op = __shfl_xor(bp, off);
            if (ov > bv || (ov == bv && op < bp)) { bv = ov; bp = op; }
        }
        if (lane == 0) {
            int pi = bp >> 3, pj = bp & 7;
            int e0 = 0, e1 = 0;
#pragma unroll
            for (int q = 0; q < 8; ++q) {
                if (pi == q) e0 = ti0[q];
                if (pj == q) e1 = ti1[q];
            }
            eidx[outbase + r] = e0 * NKEY + e1;
            gates[outbase + r] = 1.0f / (1.0f + expf(-bv));
        }
        if (lane == bp) cv = -INFINITY;
    }
}

// ---------------- K5: expert gather + compute ----------------
__global__ __launch_bounds__(512, 2) void expert_k(const float* __restrict__ x,
                                                   const float* __restrict__ down,
                                                   const float* __restrict__ up,
                                                   const int* __restrict__ eidx,
                                                   const float* __restrict__ gates,
                                                   float* __restrict__ out) {
    int t = blockIdx.x;
    int w = threadIdx.x >> 6;      // 0..7
    int lane = threadIdx.x & 63;
    __shared__ __align__(16) float4 accs[8][256];

    const float4* x4 = (const float4*)(x + (size_t)t * HDIM);
    float4 xv[4];
#pragma unroll
    for (int j = 0; j < 4; ++j) xv[j] = x4[lane + 64 * j];

    int base = t * 64 + w * 8;
    int e[8];
    float g[8];
#pragma unroll
    for (int i = 0; i < 8; ++i) {
        e[i] = eidx[base + i];
        g[i] = gates[base + i];
    }

    float dot[8];
#pragma unroll
    for (int i = 0; i < 8; ++i) dot[i] = 0.f;
#pragma unroll
    for (int i = 0; i < 8; ++i) {
        const float4* d = (const float4*)(down + (size_t)e[i] * HDIM);
#pragma unroll
        for (int j = 0; j < 4; ++j) {
            float4 dv = d[lane + 64 * j];
            dot[i] += xv[j].x * dv.x + xv[j].y * dv.y + xv[j].z * dv.z + xv[j].w * dv.w;
        }
    }

#pragma unroll
    for (int off = 32; off >= 1; off >>= 1) {
#pragma unroll
        for (int i = 0; i < 8; ++i) dot[i] += __shfl_xor(dot[i], off);
    }
    float hm[8];
#pragma unroll
    for (int i = 0; i < 8; ++i) {
        float d = dot[i];
        hm[i] = g[i] * 0.5f * d * (1.0f + erff(d * 0.70710678118654752f));
    }

    float4 acc[4];
#pragma unroll
    for (int j = 0; j < 4; ++j) acc[j] = make_float4(0.f, 0.f, 0.f, 0.f);
#pragma unroll
    for (int i = 0; i < 8; ++i) {
        const float4* u = (const float4*)(up + (size_t)e[i] * HDIM);
        float h = hm[i];
#pragma unroll
        for (int j = 0; j < 4; ++j) {
            float4 uv = u[lane + 64 * j];
            acc[j].x = fmaf(h, uv.x, acc[j].x);
            acc[j].y = fmaf(h, uv.y, acc[j].y);
            acc[j].z = fmaf(h, uv.z, acc[j].z);
            acc[j].w = fmaf(h, uv.w, acc[j].w);
        }
    }

#pragma unroll
    for (int j = 0; j < 4; ++j) accs[w][lane + 64 * j] = acc[j];
    __syncthreads();
    if (threadIdx.x < 256) {
        int s = threadIdx.x;
        float4 o = accs[0][s];
#pragma unroll
        for (int ww = 1; ww < 8; ++ww) {
            float4 r = accs[ww][s];
            o.x += r.x; o.y += r.y; o.z += r.z; o.w += r.w;
        }
        ((float4*)(out + (size_t)t * HDIM))[s] = o;
    }
}

// ---------------- launch ----------------
extern "C" void kernel_launch(void* const* d_in, const int* in_sizes, int n_in,
                              void* d_out, int out_size, void* d_ws, size_t ws_size,
                              hipStream_t stream) {
    const float* x = (const float*)d_in[0];
    const float* gamma = (const float*)d_in[1];
    const float* beta = (const float*)d_in[2];
    const float* w_q = (const float*)d_in[3];
    const float* keys = (const float*)d_in[4];
    const float* down = (const float*)d_in[5];
    const float* up = (const float*)d_in[6];
    float* out = (float*)d_out;
    float* ws = (float*)d_ws;

    // layout (float offsets)
    float* psum = ws;                         // 0 .. 65536
    float* psq = ws + 65536;                  // .. 131072
    float* scale = ws + 131072;               // 1024
    float* shift = ws + 132096;               // 1024
    int* eidx = (int*)(ws + 133120);          // 131072 ints  .. 264192
    float* gates = ws + 264192;               // 131072       .. 395264
    float* qp0 = ws + 524288;                 // 4194304      .. 4718592
    // split path: qp1 @4718592, sim @8912896 ; fallback: sim @4718592
    const size_t needed = (size_t)17301504 * 4;
    const bool split = ws_size >= needed;
    float* qp1 = ws + 4718592;
    float* sim = split ? (ws + 8912896) : (ws + 4718592);

    bn_partial_k<<<64, 256, 0, stream>>>(x, psum, psq);
    bn_final_k<<<4, 256, 0, stream>>>(psum, psq, gamma, beta, scale, shift);

    if (split) {
        // q partials: M=2048 (8 tiles), N=2048 (16 tiles), Ksplit=2
        gemm2_k<0><<<dim3(8, 16, 2), 256, 0, stream>>>(x, nullptr, w_q, qp0, scale, shift);
        // sim: M=2048 (8 tiles), N=256 (2 tiles), 16 (p,h) batches; A = qp0+qp1
        gemm2_k<1><<<dim3(8, 2, 16), 256, 0, stream>>>(qp0, qp1, keys, sim, nullptr, nullptr);
    } else {
        gemm_k<0><<<dim3(16, 16, 1), 512, 0, stream>>>(x, w_q, qp0, scale, shift,
                                                       1024, 1024, 2048, 1024);
        gemm_k<1><<<dim3(16, 2, 16), 512, 0, stream>>>(qp0, keys, sim, nullptr, nullptr,
                                                       2048, 256, 4096, 128);
    }

    topk_k<<<2048, 512, 0, stream>>>(sim, eidx, gates);
    expert_k<<<2048, 512, 0, stream>>>(x, down, up, eidx, gates, out);
}

// Round 6
// 441.937 us; speedup vs baseline: 3.7675x; 3.7675x over previous
//
#include <hip/hip_runtime.h>
#include <hip/hip_bf16.h>
#include <math.h>

// Problem constants
#define HDIM 1024      // hidden
#define TOK 2048       // B*S tokens
#define NHEAD 8
#define KD 128
#define NKEY 256
#define KSEL 8
#define NQ 2048        // 2*NH*KD
#define BN_EPS 1e-5f

// ---------------- K1: BatchNorm partial sums ----------------
__global__ __launch_bounds__(256) void bn_partial_k(const float* __restrict__ x,
                                                    float* __restrict__ psum,
                                                    float* __restrict__ psq) {
    int b = blockIdx.x;
    int t = threadIdx.x;
    float s[4] = {0.f, 0.f, 0.f, 0.f};
    float s2[4] = {0.f, 0.f, 0.f, 0.f};
    int r0 = b * 32;
    for (int r = 0; r < 32; ++r) {
        const float* row = x + (size_t)(r0 + r) * HDIM;
#pragma unroll
        for (int j = 0; j < 4; ++j) {
            float v = row[t + j * 256];
            s[j] += v;
            s2[j] += v * v;
        }
    }
#pragma unroll
    for (int j = 0; j < 4; ++j) {
        psum[b * HDIM + t + j * 256] = s[j];
        psq[b * HDIM + t + j * 256] = s2[j];
    }
}

// ---------------- K2: finalize scale/shift ----------------
__global__ __launch_bounds__(256) void bn_final_k(const float* __restrict__ psum,
                                                  const float* __restrict__ psq,
                                                  const float* __restrict__ gamma,
                                                  const float* __restrict__ beta,
                                                  float* __restrict__ scale,
                                                  float* __restrict__ shift) {
    int c = blockIdx.x * 256 + threadIdx.x;  // 0..1023
    float s = 0.f, s2 = 0.f;
    for (int b = 0; b < 64; ++b) {
        s += psum[b * HDIM + c];
        s2 += psq[b * HDIM + c];
    }
    float mean = s * (1.0f / TOK);
    float var = s2 * (1.0f / TOK) - mean * mean;
    float sc = gamma[c] * rsqrtf(var + BN_EPS);
    scale[c] = sc;
    shift[c] = beta[c] - mean * sc;
}

// ---------------- K3: 8x8 micro-tile fp32 GEMM, 128x128 tile, dbuf ----------------
// 256 threads. BK=16. No launch_bounds occupancy cap (avoid R5 spill disaster).
// MODE 0: A = x (norm on the fly), B = w_q. grid (16,16,2); z = K-split half.
//         C plane z at C + z*4194304 (2048x2048 each).
// MODE 1: A = qp0 + qp1 (split-K sum on load), B = keys slice. grid (16,2,16); z=(p,h).
template <int MODE>
__global__ __launch_bounds__(256) void gemm3_k(const float* __restrict__ A,
                                               const float* __restrict__ A2,
                                               const float* __restrict__ B,
                                               float* __restrict__ C,
                                               const float* __restrict__ scale,
                                               const float* __restrict__ shift) {
    __shared__ __align__(16) float As[2][16][128];
    __shared__ __align__(16) float Bs[2][16][128];

    const int tid = threadIdx.x;
    const int m0 = blockIdx.x * 128;
    const int n0 = blockIdx.y * 128;

    const float* Ab;
    const float* A2b = nullptr;
    const float* Bb;
    float* Cb;
    int kb, nsteps, LDA, LDB, LDC;
    if (MODE == 0) {
        LDA = 1024; LDB = 1024; LDC = 2048;
        kb = blockIdx.z * 512;
        nsteps = 32;
        Ab = A;
        Bb = B;
        Cb = C + (size_t)blockIdx.z * 4194304;
    } else {
        LDA = 2048; LDB = 256; LDC = 4096;
        kb = 0;
        nsteps = 8;
        int z = blockIdx.z;
        int p = z >> 3, h = z & 7;
        Ab = A + p * 1024 + h * 128;
        A2b = A2 + p * 1024 + h * 128;
        Bb = B + h * 65536 + p * 128;
        Cb = C + p * 2048 + h * 256;
    }

    const int sr = tid >> 1;          // 0..127: A row / B row (n or k index)
    const int sc = (tid & 1) * 8;     // 0 or 8: k-col group
    const float* ap = Ab + (size_t)(m0 + sr) * LDA + kb + sc;
    const float* ap2 = (MODE == 1) ? (A2b + (size_t)(m0 + sr) * LDA + kb + sc) : nullptr;
    const float* bp = Bb + (size_t)(n0 + sr) * LDB + kb + sc;

    float acc[8][8];
#pragma unroll
    for (int i = 0; i < 8; ++i)
#pragma unroll
        for (int j = 0; j < 8; ++j) acc[i][j] = 0.f;

    const int tm = tid >> 4;   // 0..15 -> rows tm*8..+7
    const int tn = tid & 15;   // 0..15 -> cols tn*8..+7

    // ---- stage step 0 into buf 0 ----
    {
        float4 av0 = *(const float4*)(ap);
        float4 av1 = *(const float4*)(ap + 4);
        if (MODE == 0) {
            float4 s0 = *(const float4*)(scale + kb + sc);
            float4 s1 = *(const float4*)(scale + kb + sc + 4);
            float4 h0 = *(const float4*)(shift + kb + sc);
            float4 h1 = *(const float4*)(shift + kb + sc + 4);
            av0.x = fmaf(av0.x, s0.x, h0.x); av0.y = fmaf(av0.y, s0.y, h0.y);
            av0.z = fmaf(av0.z, s0.z, h0.z); av0.w = fmaf(av0.w, s0.w, h0.w);
            av1.x = fmaf(av1.x, s1.x, h1.x); av1.y = fmaf(av1.y, s1.y, h1.y);
            av1.z = fmaf(av1.z, s1.z, h1.z); av1.w = fmaf(av1.w, s1.w, h1.w);
        } else {
            float4 a20 = *(const float4*)(ap2);
            float4 a21 = *(const float4*)(ap2 + 4);
            av0.x += a20.x; av0.y += a20.y; av0.z += a20.z; av0.w += a20.w;
            av1.x += a21.x; av1.y += a21.y; av1.z += a21.z; av1.w += a21.w;
        }
        float4 bv0 = *(const float4*)(bp);
        float4 bv1 = *(const float4*)(bp + 4);
        As[0][sc + 0][sr] = av0.x; As[0][sc + 1][sr] = av0.y;
        As[0][sc + 2][sr] = av0.z; As[0][sc + 3][sr] = av0.w;
        As[0][sc + 4][sr] = av1.x; As[0][sc + 5][sr] = av1.y;
        As[0][sc + 6][sr] = av1.z; As[0][sc + 7][sr] = av1.w;
        Bs[0][sc + 0][sr] = bv0.x; Bs[0][sc + 1][sr] = bv0.y;
        Bs[0][sc + 2][sr] = bv0.z; Bs[0][sc + 3][sr] = bv0.w;
        Bs[0][sc + 4][sr] = bv1.x; Bs[0][sc + 5][sr] = bv1.y;
        Bs[0][sc + 6][sr] = bv1.z; Bs[0][sc + 7][sr] = bv1.w;
    }
    __syncthreads();

    for (int s = 0; s < nsteps; ++s) {
        const int buf = s & 1;
        const bool more = (s + 1) < nsteps;
        float4 av0, av1, bv0, bv1;
        if (more) {
            const int kt = (s + 1) * 16;
            av0 = *(const float4*)(ap + kt);
            av1 = *(const float4*)(ap + kt + 4);
            if (MODE == 0) {
                float4 s0 = *(const float4*)(scale + kb + kt + sc);
                float4 s1 = *(const float4*)(scale + kb + kt + sc + 4);
                float4 h0 = *(const float4*)(shift + kb + kt + sc);
                float4 h1 = *(const float4*)(shift + kb + kt + sc + 4);
                av0.x = fmaf(av0.x, s0.x, h0.x); av0.y = fmaf(av0.y, s0.y, h0.y);
                av0.z = fmaf(av0.z, s0.z, h0.z); av0.w = fmaf(av0.w, s0.w, h0.w);
                av1.x = fmaf(av1.x, s1.x, h1.x); av1.y = fmaf(av1.y, s1.y, h1.y);
                av1.z = fmaf(av1.z, s1.z, h1.z); av1.w = fmaf(av1.w, s1.w, h1.w);
            } else {
                float4 a20 = *(const float4*)(ap2 + kt);
                float4 a21 = *(const float4*)(ap2 + kt + 4);
                av0.x += a20.x; av0.y += a20.y; av0.z += a20.z; av0.w += a20.w;
                av1.x += a21.x; av1.y += a21.y; av1.z += a21.z; av1.w += a21.w;
            }
            bv0 = *(const float4*)(bp + kt);
            bv1 = *(const float4*)(bp + kt + 4);
        }
#pragma unroll
        for (int kk = 0; kk < 16; ++kk) {
            float4 a0 = *(const float4*)&As[buf][kk][tm * 8];
            float4 a1 = *(const float4*)&As[buf][kk][tm * 8 + 4];
            float4 b0 = *(const float4*)&Bs[buf][kk][tn * 8];
            float4 b1 = *(const float4*)&Bs[buf][kk][tn * 8 + 4];
            float a[8] = {a0.x, a0.y, a0.z, a0.w, a1.x, a1.y, a1.z, a1.w};
            float b[8] = {b0.x, b0.y, b0.z, b0.w, b1.x, b1.y, b1.z, b1.w};
#pragma unroll
            for (int i = 0; i < 8; ++i)
#pragma unroll
                for (int j = 0; j < 8; ++j) acc[i][j] = fmaf(a[i], b[j], acc[i][j]);
        }
        if (more) {
            const int nb = buf ^ 1;
            As[nb][sc + 0][sr] = av0.x; As[nb][sc + 1][sr] = av0.y;
            As[nb][sc + 2][sr] = av0.z; As[nb][sc + 3][sr] = av0.w;
            As[nb][sc + 4][sr] = av1.x; As[nb][sc + 5][sr] = av1.y;
            As[nb][sc + 6][sr] = av1.z; As[nb][sc + 7][sr] = av1.w;
            Bs[nb][sc + 0][sr] = bv0.x; Bs[nb][sc + 1][sr] = bv0.y;
            Bs[nb][sc + 2][sr] = bv0.z; Bs[nb][sc + 3][sr] = bv0.w;
            Bs[nb][sc + 4][sr] = bv1.x; Bs[nb][sc + 5][sr] = bv1.y;
            Bs[nb][sc + 6][sr] = bv1.z; Bs[nb][sc + 7][sr] = bv1.w;
            __syncthreads();
        }
    }

#pragma unroll
    for (int i = 0; i < 8; ++i) {
        float* crow = Cb + (size_t)(m0 + tm * 8 + i) * LDC + n0 + tn * 8;
        *(float4*)(crow) = make_float4(acc[i][0], acc[i][1], acc[i][2], acc[i][3]);
        *(float4*)(crow + 4) = make_float4(acc[i][4], acc[i][5], acc[i][6], acc[i][7]);
    }
}

// ---------------- K4: top-k per (token, head) ----------------
__global__ __launch_bounds__(512) void topk_k(const float* __restrict__ sim,
                                              int* __restrict__ eidx,
                                              float* __restrict__ gates) {
    int t = blockIdx.x;
    int h = threadIdx.x >> 6;
    int lane = threadIdx.x & 63;
    const float* s0p = sim + (size_t)t * 4096 + h * 256;
    const float* s1p = s0p + 2048;
    float4 v0 = *(const float4*)(s0p + lane * 4);
    float4 v1 = *(const float4*)(s1p + lane * 4);
    float c0[4] = {v0.x, v0.y, v0.z, v0.w};
    float c1[4] = {v1.x, v1.y, v1.z, v1.w};

    float tv0[8], tv1[8];
    int ti0[8], ti1[8];

#pragma unroll
    for (int r = 0; r < 8; ++r) {
        float bv = c0[0];
        int bi = lane * 4;
#pragma unroll
        for (int j = 1; j < 4; ++j)
            if (c0[j] > bv) { bv = c0[j]; bi = lane * 4 + j; }
#pragma unroll
        for (int off = 1; off < 64; off <<= 1) {
            float ov = __shfl_xor(bv, off);
            int oi = __shfl_xor(bi, off);
            if (ov > bv || (ov == bv && oi < bi)) { bv = ov; bi = oi; }
        }
        tv0[r] = bv;
        ti0[r] = bi;
        if ((bi >> 2) == lane) {
            int jj = bi & 3;
#pragma unroll
            for (int q = 0; q < 4; ++q)
                if (q == jj) c0[q] = -INFINITY;
        }
    }
#pragma unroll
    for (int r = 0; r < 8; ++r) {
        float bv = c1[0];
        int bi = lane * 4;
#pragma unroll
        for (int j = 1; j < 4; ++j)
            if (c1[j] > bv) { bv = c1[j]; bi = lane * 4 + j; }
#pragma unroll
        for (int off = 1; off < 64; off <<= 1) {
            float ov = __shfl_xor(bv, off);
            int oi = __shfl_xor(bi, off);
            if (ov > bv || (ov == bv && oi < bi)) { bv = ov; bi = oi; }
        }
        tv1[r] = bv;
        ti1[r] = bi;
        if ((bi >> 2) == lane) {
            int jj = bi & 3;
#pragma unroll
            for (int q = 0; q < 4; ++q)
                if (q == jj) c1[q] = -INFINITY;
        }
    }

    int ii = lane >> 3, jj = lane & 7;
    float a = -INFINITY, b = -INFINITY;
#pragma unroll
    for (int r = 0; r < 8; ++r) {
        if (ii == r) a = tv0[r];
        if (jj == r) b = tv1[r];
    }
    float cv = a + b;
    int cpos = lane;

    int outbase = (t * NHEAD + h) * KSEL;
#pragma unroll
    for (int r = 0; r < 8; ++r) {
        float bv = cv;
        int bp = cpos;
#pragma unroll
        for (int off = 1; off < 64; off <<= 1) {
            float ov = __shfl_xor(bv, off);
            int op = __shfl_xor(bp, off);
            if (ov > bv || (ov == bv && op < bp)) { bv = ov; bp = op; }
        }
        if (lane == 0) {
            int pi = bp >> 3, pj = bp & 7;
            int e0 = 0, e1 = 0;
#pragma unroll
            for (int q = 0; q < 8; ++q) {
                if (pi == q) e0 = ti0[q];
                if (pj == q) e1 = ti1[q];
            }
            eidx[outbase + r] = e0 * NKEY + e1;
            gates[outbase + r] = 1.0f / (1.0f + expf(-bv));
        }
        if (lane == bp) cv = -INFINITY;
    }
}

// ---------------- K5: expert gather + compute ----------------
__global__ __launch_bounds__(512, 2) void expert_k(const float* __restrict__ x,
                                                   const float* __restrict__ down,
                                                   const float* __restrict__ up,
                                                   const int* __restrict__ eidx,
                                                   const float* __restrict__ gates,
                                                   float* __restrict__ out) {
    int t = blockIdx.x;
    int w = threadIdx.x >> 6;      // 0..7
    int lane = threadIdx.x & 63;
    __shared__ __align__(16) float4 accs[8][256];

    const float4* x4 = (const float4*)(x + (size_t)t * HDIM);
    float4 xv[4];
#pragma unroll
    for (int j = 0; j < 4; ++j) xv[j] = x4[lane + 64 * j];

    int base = t * 64 + w * 8;
    int e[8];
    float g[8];
#pragma unroll
    for (int i = 0; i < 8; ++i) {
        e[i] = eidx[base + i];
        g[i] = gates[base + i];
    }

    float dot[8];
#pragma unroll
    for (int i = 0; i < 8; ++i) dot[i] = 0.f;
#pragma unroll
    for (int i = 0; i < 8; ++i) {
        const float4* d = (const float4*)(down + (size_t)e[i] * HDIM);
#pragma unroll
        for (int j = 0; j < 4; ++j) {
            float4 dv = d[lane + 64 * j];
            dot[i] += xv[j].x * dv.x + xv[j].y * dv.y + xv[j].z * dv.z + xv[j].w * dv.w;
        }
    }

#pragma unroll
    for (int off = 32; off >= 1; off >>= 1) {
#pragma unroll
        for (int i = 0; i < 8; ++i) dot[i] += __shfl_xor(dot[i], off);
    }
    float hm[8];
#pragma unroll
    for (int i = 0; i < 8; ++i) {
        float d = dot[i];
        hm[i] = g[i] * 0.5f * d * (1.0f + erff(d * 0.70710678118654752f));
    }

    float4 acc[4];
#pragma unroll
    for (int j = 0; j < 4; ++j) acc[j] = make_float4(0.f, 0.f, 0.f, 0.f);
#pragma unroll
    for (int i = 0; i < 8; ++i) {
        const float4* u = (const float4*)(up + (size_t)e[i] * HDIM);
        float h = hm[i];
#pragma unroll
        for (int j = 0; j < 4; ++j) {
            float4 uv = u[lane + 64 * j];
            acc[j].x = fmaf(h, uv.x, acc[j].x);
            acc[j].y = fmaf(h, uv.y, acc[j].y);
            acc[j].z = fmaf(h, uv.z, acc[j].z);
            acc[j].w = fmaf(h, uv.w, acc[j].w);
        }
    }

#pragma unroll
    for (int j = 0; j < 4; ++j) accs[w][lane + 64 * j] = acc[j];
    __syncthreads();
    if (threadIdx.x < 256) {
        int s = threadIdx.x;
        float4 o = accs[0][s];
#pragma unroll
        for (int ww = 1; ww < 8; ++ww) {
            float4 r = accs[ww][s];
            o.x += r.x; o.y += r.y; o.z += r.z; o.w += r.w;
        }
        ((float4*)(out + (size_t)t * HDIM))[s] = o;
    }
}

// ---------------- launch ----------------
extern "C" void kernel_launch(void* const* d_in, const int* in_sizes, int n_in,
                              void* d_out, int out_size, void* d_ws, size_t ws_size,
                              hipStream_t stream) {
    const float* x = (const float*)d_in[0];
    const float* gamma = (const float*)d_in[1];
    const float* beta = (const float*)d_in[2];
    const float* w_q = (const float*)d_in[3];
    const float* keys = (const float*)d_in[4];
    const float* down = (const float*)d_in[5];
    const float* up = (const float*)d_in[6];
    float* out = (float*)d_out;
    float* ws = (float*)d_ws;

    // layout (float offsets) — split-K path proven within ws in R5
    float* psum = ws;                         // 0 .. 65536
    float* psq = ws + 65536;                  // .. 131072
    float* scale = ws + 131072;               // 1024
    float* shift = ws + 132096;               // 1024
    int* eidx = (int*)(ws + 133120);          // 131072 ints  .. 264192
    float* gates = ws + 264192;               // 131072       .. 395264
    float* qp0 = ws + 524288;                 // plane 0: 2048x2048
    float* qp1 = ws + 4718592;                // plane 1: 2048x2048
    float* sim = ws + 8912896;                // 2048x4096

    bn_partial_k<<<64, 256, 0, stream>>>(x, psum, psq);
    bn_final_k<<<4, 256, 0, stream>>>(psum, psq, gamma, beta, scale, shift);

    // q partials: M=2048 (16 tiles), N=2048 (16 tiles), Ksplit=2 -> 512 blocks
    gemm3_k<0><<<dim3(16, 16, 2), 256, 0, stream>>>(x, nullptr, w_q, qp0, scale, shift);
    // sim: M=2048 (16 tiles), N=256 (2 tiles), 16 (p,h) batches; A = qp0+qp1
    gemm3_k<1><<<dim3(16, 2, 16), 256, 0, stream>>>(qp0, qp1, keys, sim, nullptr, nullptr);

    topk_k<<<2048, 512, 0, stream>>>(sim, eidx, gates);
    expert_k<<<2048, 512, 0, stream>>>(x, down, up, eidx, gates, out);
}

// Round 7
// 380.843 us; speedup vs baseline: 4.3719x; 1.1604x over previous
//
#include <hip/hip_runtime.h>
#include <hip/hip_bf16.h>
#include <math.h>

// Problem constants
#define HDIM 1024      // hidden
#define TOK 2048       // B*S tokens
#define NHEAD 8
#define KD 128
#define NKEY 256
#define KSEL 8
#define NQ 2048        // 2*NH*KD
#define BN_EPS 1e-5f

// ---------------- K1: BatchNorm partial sums ----------------
__global__ __launch_bounds__(256) void bn_partial_k(const float* __restrict__ x,
                                                    float* __restrict__ psum,
                                                    float* __restrict__ psq) {
    int b = blockIdx.x;
    int t = threadIdx.x;
    float s[4] = {0.f, 0.f, 0.f, 0.f};
    float s2[4] = {0.f, 0.f, 0.f, 0.f};
    int r0 = b * 32;
    for (int r = 0; r < 32; ++r) {
        const float* row = x + (size_t)(r0 + r) * HDIM;
#pragma unroll
        for (int j = 0; j < 4; ++j) {
            float v = row[t + j * 256];
            s[j] += v;
            s2[j] += v * v;
        }
    }
#pragma unroll
    for (int j = 0; j < 4; ++j) {
        psum[b * HDIM + t + j * 256] = s[j];
        psq[b * HDIM + t + j * 256] = s2[j];
    }
}

// ---------------- K2: finalize scale/shift ----------------
__global__ __launch_bounds__(256) void bn_final_k(const float* __restrict__ psum,
                                                  const float* __restrict__ psq,
                                                  const float* __restrict__ gamma,
                                                  const float* __restrict__ beta,
                                                  float* __restrict__ scale,
                                                  float* __restrict__ shift) {
    int c = blockIdx.x * 256 + threadIdx.x;  // 0..1023
    float s = 0.f, s2 = 0.f;
    for (int b = 0; b < 64; ++b) {
        s += psum[b * HDIM + c];
        s2 += psq[b * HDIM + c];
    }
    float mean = s * (1.0f / TOK);
    float var = s2 * (1.0f / TOK) - mean * mean;
    float sc = gamma[c] * rsqrtf(var + BN_EPS);
    scale[c] = sc;
    shift[c] = beta[c] - mean * sc;
}

// ---------------- K3: tiled fp32 GEMM (R4 structure) + split-K ----------------
// 512 threads; 128x128 tile, BK=16, micro 8x4, LDS ping-pong, one barrier/step.
// MODE 0: A = x (norm on the fly), B = w_q. grid (16,16,2); z = K-half.
//         C plane z at C + z*4194304 (2048x2048 each). K-half = 512.
// MODE 1: A = qp0 + qp1 (summed on load), B = keys slice. grid (16,2,16); z=(p,h). K=128.
template <int MODE>
__global__ __launch_bounds__(512) void gemm_k(const float* __restrict__ A,
                                              const float* __restrict__ A2,
                                              const float* __restrict__ B,
                                              float* __restrict__ C,
                                              const float* __restrict__ scale,
                                              const float* __restrict__ shift) {
    __shared__ __align__(16) float As[2][16][128];
    __shared__ __align__(16) float Bs[2][16][128];

    const int tid = threadIdx.x;
    const int m0 = blockIdx.x * 128;
    const int n0 = blockIdx.y * 128;

    const float* Ab;
    const float* A2b = nullptr;
    const float* Bb;
    float* Cb;
    int kb, NS, lda, ldb, ldc;
    if (MODE == 0) {
        lda = 1024; ldb = 1024; ldc = 2048;
        kb = blockIdx.z * 512;
        NS = 32;
        Ab = A;
        Bb = B;
        Cb = C + (size_t)blockIdx.z * 4194304;
    } else {
        lda = 2048; ldb = 256; ldc = 4096;
        kb = 0;
        NS = 8;
        int z = blockIdx.z;
        int p = z >> 3, h = z & 7;
        Ab = A + p * 1024 + h * 128;
        A2b = A2 + p * 1024 + h * 128;
        Bb = B + h * 65536 + p * 128;
        Cb = C + p * 2048 + h * 256;
    }

    const int lr = tid >> 2;        // 0..127
    const int lc = (tid & 3) * 4;   // 0,4,8,12
    const int tm = tid >> 5;        // 0..15
    const int tn = tid & 31;        // 0..31

    float acc[8][4] = {};

    const float* arow = Ab + (size_t)(m0 + lr) * lda + kb + lc;
    const float* arow2 = (MODE == 1) ? (A2b + (size_t)(m0 + lr) * lda + lc) : nullptr;
    const float* brow = Bb + (size_t)(n0 + lr) * ldb + kb + lc;

    // prologue: stage step 0
    {
        float4 av = *(const float4*)(arow);
        if (MODE == 0) {
            float4 s4 = *(const float4*)(scale + kb + lc);
            float4 h4 = *(const float4*)(shift + kb + lc);
            av.x = fmaf(av.x, s4.x, h4.x);
            av.y = fmaf(av.y, s4.y, h4.y);
            av.z = fmaf(av.z, s4.z, h4.z);
            av.w = fmaf(av.w, s4.w, h4.w);
        } else {
            float4 a2 = *(const float4*)(arow2);
            av.x += a2.x; av.y += a2.y; av.z += a2.z; av.w += a2.w;
        }
        float4 bv = *(const float4*)(brow);
        As[0][lc + 0][lr] = av.x;
        As[0][lc + 1][lr] = av.y;
        As[0][lc + 2][lr] = av.z;
        As[0][lc + 3][lr] = av.w;
        Bs[0][lc + 0][lr] = bv.x;
        Bs[0][lc + 1][lr] = bv.y;
        Bs[0][lc + 2][lr] = bv.z;
        Bs[0][lc + 3][lr] = bv.w;
    }
    __syncthreads();

    for (int s = 0; s < NS; ++s) {
        const int buf = s & 1;
        float4 av, bv;
        const bool more = (s + 1) < NS;
        if (more) {
            int kt = (s + 1) << 4;
            av = *(const float4*)(arow + kt);
            if (MODE == 0) {
                float4 s4 = *(const float4*)(scale + kb + kt + lc);
                float4 h4 = *(const float4*)(shift + kb + kt + lc);
                av.x = fmaf(av.x, s4.x, h4.x);
                av.y = fmaf(av.y, s4.y, h4.y);
                av.z = fmaf(av.z, s4.z, h4.z);
                av.w = fmaf(av.w, s4.w, h4.w);
            } else {
                float4 a2 = *(const float4*)(arow2 + kt);
                av.x += a2.x; av.y += a2.y; av.z += a2.z; av.w += a2.w;
            }
            bv = *(const float4*)(brow + kt);
        }
#pragma unroll
        for (int kk = 0; kk < 16; ++kk) {
            float4 a0 = *(const float4*)&As[buf][kk][tm * 8];
            float4 a1 = *(const float4*)&As[buf][kk][tm * 8 + 4];
            float4 b0 = *(const float4*)&Bs[buf][kk][tn * 4];
            float a[8] = {a0.x, a0.y, a0.z, a0.w, a1.x, a1.y, a1.z, a1.w};
            float b[4] = {b0.x, b0.y, b0.z, b0.w};
#pragma unroll
            for (int i = 0; i < 8; ++i)
#pragma unroll
                for (int j = 0; j < 4; ++j) acc[i][j] = fmaf(a[i], b[j], acc[i][j]);
        }
        if (more) {
            const int nb = buf ^ 1;
            As[nb][lc + 0][lr] = av.x;
            As[nb][lc + 1][lr] = av.y;
            As[nb][lc + 2][lr] = av.z;
            As[nb][lc + 3][lr] = av.w;
            Bs[nb][lc + 0][lr] = bv.x;
            Bs[nb][lc + 1][lr] = bv.y;
            Bs[nb][lc + 2][lr] = bv.z;
            Bs[nb][lc + 3][lr] = bv.w;
            __syncthreads();
        }
    }
#pragma unroll
    for (int i = 0; i < 8; ++i) {
        float4 o = make_float4(acc[i][0], acc[i][1], acc[i][2], acc[i][3]);
        *(float4*)(Cb + (size_t)(m0 + tm * 8 + i) * ldc + n0 + tn * 4) = o;
    }
}

// ---------------- K4: top-k per (token, head) ----------------
__global__ __launch_bounds__(512) void topk_k(const float* __restrict__ sim,
                                              int* __restrict__ eidx,
                                              float* __restrict__ gates) {
    int t = blockIdx.x;
    int h = threadIdx.x >> 6;
    int lane = threadIdx.x & 63;
    const float* s0p = sim + (size_t)t * 4096 + h * 256;
    const float* s1p = s0p + 2048;
    float4 v0 = *(const float4*)(s0p + lane * 4);
    float4 v1 = *(const float4*)(s1p + lane * 4);
    float c0[4] = {v0.x, v0.y, v0.z, v0.w};
    float c1[4] = {v1.x, v1.y, v1.z, v1.w};

    float tv0[8], tv1[8];
    int ti0[8], ti1[8];

#pragma unroll
    for (int r = 0; r < 8; ++r) {
        float bv = c0[0];
        int bi = lane * 4;
#pragma unroll
        for (int j = 1; j < 4; ++j)
            if (c0[j] > bv) { bv = c0[j]; bi = lane * 4 + j; }
#pragma unroll
        for (int off = 1; off < 64; off <<= 1) {
            float ov = __shfl_xor(bv, off);
            int oi = __shfl_xor(bi, off);
            if (ov > bv || (ov == bv && oi < bi)) { bv = ov; bi = oi; }
        }
        tv0[r] = bv;
        ti0[r] = bi;
        if ((bi >> 2) == lane) {
            int jj = bi & 3;
#pragma unroll
            for (int q = 0; q < 4; ++q)
                if (q == jj) c0[q] = -INFINITY;
        }
    }
#pragma unroll
    for (int r = 0; r < 8; ++r) {
        float bv = c1[0];
        int bi = lane * 4;
#pragma unroll
        for (int j = 1; j < 4; ++j)
            if (c1[j] > bv) { bv = c1[j]; bi = lane * 4 + j; }
#pragma unroll
        for (int off = 1; off < 64; off <<= 1) {
            float ov = __shfl_xor(bv, off);
            int oi = __shfl_xor(bi, off);
            if (ov > bv || (ov == bv && oi < bi)) { bv = ov; bi = oi; }
        }
        tv1[r] = bv;
        ti1[r] = bi;
        if ((bi >> 2) == lane) {
            int jj = bi & 3;
#pragma unroll
            for (int q = 0; q < 4; ++q)
                if (q == jj) c1[q] = -INFINITY;
        }
    }

    int ii = lane >> 3, jj = lane & 7;
    float a = -INFINITY, b = -INFINITY;
#pragma unroll
    for (int r = 0; r < 8; ++r) {
        if (ii == r) a = tv0[r];
        if (jj == r) b = tv1[r];
    }
    float cv = a + b;
    int cpos = lane;

    int outbase = (t * NHEAD + h) * KSEL;
#pragma unroll
    for (int r = 0; r < 8; ++r) {
        float bv = cv;
        int bp = cpos;
#pragma unroll
        for (int off = 1; off < 64; off <<= 1) {
            float ov = __shfl_xor(bv, off);
            int op = __shfl_xor(bp, off);
            if (ov > bv || (ov == bv && op < bp)) { bv = ov; bp = op; }
        }
        if (lane == 0) {
            int pi = bp >> 3, pj = bp & 7;
            int e0 = 0, e1 = 0;
#pragma unroll
            for (int q = 0; q < 8; ++q) {
                if (pi == q) e0 = ti0[q];
                if (pj == q) e1 = ti1[q];
            }
            eidx[outbase + r] = e0 * NKEY + e1;
            gates[outbase + r] = 1.0f / (1.0f + expf(-bv));
        }
        if (lane == bp) cv = -INFINITY;
    }
}

// ---------------- K5: expert gather + compute ----------------
__global__ __launch_bounds__(512, 2) void expert_k(const float* __restrict__ x,
                                                   const float* __restrict__ down,
                                                   const float* __restrict__ up,
                                                   const int* __restrict__ eidx,
                                                   const float* __restrict__ gates,
                                                   float* __restrict__ out) {
    int t = blockIdx.x;
    int w = threadIdx.x >> 6;      // 0..7
    int lane = threadIdx.x & 63;
    __shared__ __align__(16) float4 accs[8][256];

    const float4* x4 = (const float4*)(x + (size_t)t * HDIM);
    float4 xv[4];
#pragma unroll
    for (int j = 0; j < 4; ++j) xv[j] = x4[lane + 64 * j];

    int base = t * 64 + w * 8;
    int e[8];
    float g[8];
#pragma unroll
    for (int i = 0; i < 8; ++i) {
        e[i] = eidx[base + i];
        g[i] = gates[base + i];
    }

    float dot[8];
#pragma unroll
    for (int i = 0; i < 8; ++i) dot[i] = 0.f;
#pragma unroll
    for (int i = 0; i < 8; ++i) {
        const float4* d = (const float4*)(down + (size_t)e[i] * HDIM);
#pragma unroll
        for (int j = 0; j < 4; ++j) {
            float4 dv = d[lane + 64 * j];
            dot[i] += xv[j].x * dv.x + xv[j].y * dv.y + xv[j].z * dv.z + xv[j].w * dv.w;
        }
    }

#pragma unroll
    for (int off = 32; off >= 1; off >>= 1) {
#pragma unroll
        for (int i = 0; i < 8; ++i) dot[i] += __shfl_xor(dot[i], off);
    }
    float hm[8];
#pragma unroll
    for (int i = 0; i < 8; ++i) {
        float d = dot[i];
        hm[i] = g[i] * 0.5f * d * (1.0f + erff(d * 0.70710678118654752f));
    }

    float4 acc[4];
#pragma unroll
    for (int j = 0; j < 4; ++j) acc[j] = make_float4(0.f, 0.f, 0.f, 0.f);
#pragma unroll
    for (int i = 0; i < 8; ++i) {
        const float4* u = (const float4*)(up + (size_t)e[i] * HDIM);
        float h = hm[i];
#pragma unroll
        for (int j = 0; j < 4; ++j) {
            float4 uv = u[lane + 64 * j];
            acc[j].x = fmaf(h, uv.x, acc[j].x);
            acc[j].y = fmaf(h, uv.y, acc[j].y);
            acc[j].z = fmaf(h, uv.z, acc[j].z);
            acc[j].w = fmaf(h, uv.w, acc[j].w);
        }
    }

#pragma unroll
    for (int j = 0; j < 4; ++j) accs[w][lane + 64 * j] = acc[j];
    __syncthreads();
    if (threadIdx.x < 256) {
        int s = threadIdx.x;
        float4 o = accs[0][s];
#pragma unroll
        for (int ww = 1; ww < 8; ++ww) {
            float4 r = accs[ww][s];
            o.x += r.x; o.y += r.y; o.z += r.z; o.w += r.w;
        }
        ((float4*)(out + (size_t)t * HDIM))[s] = o;
    }
}

// ---------------- launch ----------------
extern "C" void kernel_launch(void* const* d_in, const int* in_sizes, int n_in,
                              void* d_out, int out_size, void* d_ws, size_t ws_size,
                              hipStream_t stream) {
    const float* x = (const float*)d_in[0];
    const float* gamma = (const float*)d_in[1];
    const float* beta = (const float*)d_in[2];
    const float* w_q = (const float*)d_in[3];
    const float* keys = (const float*)d_in[4];
    const float* down = (const float*)d_in[5];
    const float* up = (const float*)d_in[6];
    float* out = (float*)d_out;
    float* ws = (float*)d_ws;

    // layout (float offsets) — 69.2 MB total, proven to fit in R5/R6
    float* psum = ws;                         // 0 .. 65536
    float* psq = ws + 65536;                  // .. 131072
    float* scale = ws + 131072;               // 1024
    float* shift = ws + 132096;               // 1024
    int* eidx = (int*)(ws + 133120);          // 131072 ints  .. 264192
    float* gates = ws + 264192;               // 131072       .. 395264
    float* qp0 = ws + 524288;                 // plane 0: 2048x2048
    float* qp1 = ws + 4718592;                // plane 1: 2048x2048
    float* sim = ws + 8912896;                // 2048x4096

    bn_partial_k<<<64, 256, 0, stream>>>(x, psum, psq);
    bn_final_k<<<4, 256, 0, stream>>>(psum, psq, gamma, beta, scale, shift);

    // q partials: M=2048 (16 tiles), N=2048 (16 tiles), Ksplit=2 -> 512 blocks
    gemm_k<0><<<dim3(16, 16, 2), 512, 0, stream>>>(x, nullptr, w_q, qp0, scale, shift);
    // sim: M=2048 (16 tiles), N=256 (2 tiles), 16 (p,h) batches; A = qp0+qp1
    gemm_k<1><<<dim3(16, 2, 16), 512, 0, stream>>>(qp0, qp1, keys, sim, nullptr, nullptr);

    topk_k<<<2048, 512, 0, stream>>>(sim, eidx, gates);
    expert_k<<<2048, 512, 0, stream>>>(x, down, up, eidx, gates, out);
}

// Round 9
// 285.663 us; speedup vs baseline: 5.8285x; 1.3332x over previous
//
#include <hip/hip_runtime.h>
#include <hip/hip_bf16.h>
#include <math.h>

// Problem constants
#define HDIM 1024
#define TOK 2048
#define NHEAD 8
#define KD 128
#define NKEY 256
#define KSEL 8
#define BN_EPS 1e-5f

typedef _Float16 half8 __attribute__((ext_vector_type(8)));
typedef float floatx4 __attribute__((ext_vector_type(4)));

// split fp32 -> (hi f16, lo f16 scaled by 2^11), packed hi | lo<<16
__device__ __forceinline__ uint32_t pack_f16pair(float v) {
    _Float16 h = (_Float16)v;
    float hf = (float)h;
    _Float16 l = (_Float16)((v - hf) * 2048.0f);
    return (uint32_t)__builtin_bit_cast(unsigned short, h) |
           ((uint32_t)__builtin_bit_cast(unsigned short, l) << 16);
}

// ---------------- K1: BatchNorm partial sums ----------------
__global__ __launch_bounds__(256) void bn_partial_k(const float* __restrict__ x,
                                                    float* __restrict__ psum,
                                                    float* __restrict__ psq) {
    int b = blockIdx.x;
    int t = threadIdx.x;
    float s[4] = {0.f, 0.f, 0.f, 0.f};
    float s2[4] = {0.f, 0.f, 0.f, 0.f};
    int r0 = b * 32;
    for (int r = 0; r < 32; ++r) {
        const float* row = x + (size_t)(r0 + r) * HDIM;
#pragma unroll
        for (int j = 0; j < 4; ++j) {
            float v = row[t + j * 256];
            s[j] += v;
            s2[j] += v * v;
        }
    }
#pragma unroll
    for (int j = 0; j < 4; ++j) {
        psum[b * HDIM + t + j * 256] = s[j];
        psq[b * HDIM + t + j * 256] = s2[j];
    }
}

// ---------------- K2: finalize scale/shift ----------------
__global__ __launch_bounds__(256) void bn_final_k(const float* __restrict__ psum,
                                                  const float* __restrict__ psq,
                                                  const float* __restrict__ gamma,
                                                  const float* __restrict__ beta,
                                                  float* __restrict__ scale,
                                                  float* __restrict__ shift) {
    int c = blockIdx.x * 256 + threadIdx.x;
    float s = 0.f, s2 = 0.f;
    for (int b = 0; b < 64; ++b) {
        s += psum[b * HDIM + c];
        s2 += psq[b * HDIM + c];
    }
    float mean = s * (1.0f / TOK);
    float var = s2 * (1.0f / TOK) - mean * mean;
    float sc = gamma[c] * rsqrtf(var + BN_EPS);
    scale[c] = sc;
    shift[c] = beta[c] - mean * sc;
}

// ---------------- cvt: fp32 -> packed f16-pair (optionally normalized) ----------
template <int NORM>
__global__ __launch_bounds__(256) void cvt_pack_k(const float* __restrict__ in,
                                                  uint32_t* __restrict__ out,
                                                  const float* __restrict__ sc,
                                                  const float* __restrict__ sh) {
    int i = (blockIdx.x * 256 + threadIdx.x) * 4;
    float4 v = *(const float4*)(in + i);
    if (NORM) {
        int c = i & 1023;
        float4 s4 = *(const float4*)(sc + c);
        float4 h4 = *(const float4*)(sh + c);
        v.x = fmaf(v.x, s4.x, h4.x);
        v.y = fmaf(v.y, s4.y, h4.y);
        v.z = fmaf(v.z, s4.z, h4.z);
        v.w = fmaf(v.w, s4.w, h4.w);
    }
    uint4 o;
    o.x = pack_f16pair(v.x);
    o.y = pack_f16pair(v.y);
    o.z = pack_f16pair(v.z);
    o.w = pack_f16pair(v.w);
    *(uint4*)(out + i) = o;
}

// keys [h][nk][p][d] fp32 -> kpk [(h*2+p)][nk][d] packed
__global__ __launch_bounds__(256) void cvt_keys_k(const float* __restrict__ in,
                                                  uint32_t* __restrict__ out) {
    int i = blockIdx.x * 256 + threadIdx.x;  // 524288 total
    int d = i & 127;
    int nk = (i >> 7) & 255;
    int hp = i >> 15;
    int h = hp >> 1, p = hp & 1;
    out[i] = pack_f16pair(in[h * 65536 + nk * 256 + p * 128 + d]);
}

// ---------------- MFMA GEMM: C = A * B^T via 3-term f16 split ----------------
// A, B packed u32 (hi|lo f16). 512 threads = 8 waves (2m x 4n), tile 128x128, BK=32.
// MODE 0: q GEMM  M=N=2048 K=1024, grid (16,16,1), C -> packed u32 qpk (ldc 2048)
// MODE 1: sim GEMM per z=(p,h): K=128, grid (16,2,16), C -> fp32 sim (ldc 4096)
template <int MODE>
__global__ __launch_bounds__(512) void mgemm_k(const uint32_t* __restrict__ A,
                                               const uint32_t* __restrict__ B,
                                               float* __restrict__ Cf,
                                               uint32_t* __restrict__ Cp) {
    __shared__ _Float16 Ah[128][40];
    __shared__ _Float16 Al[128][40];
    __shared__ _Float16 Bh[128][40];
    __shared__ _Float16 Bl[128][40];

    const int tid = threadIdx.x;
    const int m0 = blockIdx.x * 128;
    const int n0 = blockIdx.y * 128;

    const uint32_t* Ab;
    const uint32_t* Bb;
    int lda, ldb, NS, ldc;
    size_t cbase;
    if (MODE == 0) {
        lda = 1024; ldb = 1024; NS = 32; ldc = 2048; cbase = 0;
        Ab = A; Bb = B;
    } else {
        lda = 2048; ldb = 128; NS = 4; ldc = 4096;
        int z = blockIdx.z, p = z >> 3, h = z & 7;
        Ab = A + p * 1024 + h * 128;
        Bb = B + (size_t)(h * 2 + p) * 32768;
        cbase = p * 2048 + h * 256;
    }

    // staging: waves 0-3 stage A (block rows m0..m0+127), waves 4-7 stage B (n0..n0+127)
    const int st = tid & 255;
    const int srow = st >> 1;
    const int skh = (st & 1) * 16;
    const bool isB = (tid >= 256);
    const uint32_t* sp = (isB ? (Bb + (size_t)(n0 + srow) * ldb)
                              : (Ab + (size_t)(m0 + srow) * lda)) + skh;   // R8 bugfix: +m0/+n0
    _Float16* Hp = isB ? &Bh[srow][skh] : &Ah[srow][skh];
    _Float16* Lp = isB ? &Bl[srow][skh] : &Al[srow][skh];

    const int w = tid >> 6, lane = tid & 63;
    const int wm = w >> 2, wn = w & 3;          // wave sub-tile 64(m) x 32(n)
    const int fr = lane & 15, kg = lane >> 4;   // frag row/col, k-group

    floatx4 acc1[4][2];  // hi*hi
    floatx4 acc2[4][2];  // cross terms (scaled by 2^11)
#pragma unroll
    for (int i = 0; i < 4; ++i)
#pragma unroll
        for (int j = 0; j < 2; ++j) {
            acc1[i][j] = (floatx4)0.0f;
            acc2[i][j] = (floatx4)0.0f;
        }

    uint32_t rg[16];
    auto gload = [&](int s) {
        const uint32_t* p = sp + s * 32;
#pragma unroll
        for (int j = 0; j < 4; ++j) *(uint4*)&rg[j * 4] = *(const uint4*)(p + j * 4);
    };
    auto lwrite = [&]() {
        uint32_t hh[8], ll[8];
#pragma unroll
        for (int j = 0; j < 8; ++j) {
            hh[j] = __builtin_amdgcn_perm(rg[2 * j + 1], rg[2 * j], 0x05040100u);
            ll[j] = __builtin_amdgcn_perm(rg[2 * j + 1], rg[2 * j], 0x07060302u);
        }
        *(uint4*)(Hp) = *(uint4*)&hh[0];
        *(uint4*)(Hp + 8) = *(uint4*)&hh[4];
        *(uint4*)(Lp) = *(uint4*)&ll[0];
        *(uint4*)(Lp + 8) = *(uint4*)&ll[4];
    };

    gload(0);
    lwrite();
    for (int s = 0; s < NS; ++s) {
        if (s + 1 < NS) gload(s + 1);     // issue next-tile global loads early
        __syncthreads();                  // tile s LDS writes visible
        half8 ah[4], al[4], bh2[2], bl2[2];
#pragma unroll
        for (int mf = 0; mf < 4; ++mf) {
            int r = wm * 64 + mf * 16 + fr;
            ah[mf] = *(const half8*)&Ah[r][kg * 8];
            al[mf] = *(const half8*)&Al[r][kg * 8];
        }
#pragma unroll
        for (int nf = 0; nf < 2; ++nf) {
            int r = wn * 32 + nf * 16 + fr;
            bh2[nf] = *(const half8*)&Bh[r][kg * 8];
            bl2[nf] = *(const half8*)&Bl[r][kg * 8];
        }
#pragma unroll
        for (int mf = 0; mf < 4; ++mf)
#pragma unroll
            for (int nf = 0; nf < 2; ++nf) {
                acc1[mf][nf] = __builtin_amdgcn_mfma_f32_16x16x32_f16(ah[mf], bh2[nf], acc1[mf][nf], 0, 0, 0);
                acc2[mf][nf] = __builtin_amdgcn_mfma_f32_16x16x32_f16(ah[mf], bl2[nf], acc2[mf][nf], 0, 0, 0);
                acc2[mf][nf] = __builtin_amdgcn_mfma_f32_16x16x32_f16(al[mf], bh2[nf], acc2[mf][nf], 0, 0, 0);
            }
        __syncthreads();                  // all reads of tile s done
        if (s + 1 < NS) lwrite();
    }

    // epilogue: C/D layout col=lane&15, row=(lane>>4)*4+reg  [m89-verified]
#pragma unroll
    for (int mf = 0; mf < 4; ++mf)
#pragma unroll
        for (int nf = 0; nf < 2; ++nf)
#pragma unroll
            for (int r = 0; r < 4; ++r) {
                float q = acc1[mf][nf][r] + acc2[mf][nf][r] * (1.0f / 2048.0f);
                int row = m0 + wm * 64 + mf * 16 + kg * 4 + r;
                int col = n0 + wn * 32 + nf * 16 + fr;
                if (MODE == 0)
                    Cp[(size_t)row * 2048 + col] = pack_f16pair(q);
                else
                    Cf[cbase + (size_t)row * (size_t)ldc + col] = q;
            }
}

// ---------------- K4: top-k per (token, head) ----------------
__global__ __launch_bounds__(512) void topk_k(const float* __restrict__ sim,
                                              int* __restrict__ eidx,
                                              float* __restrict__ gates) {
    int t = blockIdx.x;
    int h = threadIdx.x >> 6;
    int lane = threadIdx.x & 63;
    const float* s0p = sim + (size_t)t * 4096 + h * 256;
    const float* s1p = s0p + 2048;
    float4 v0 = *(const float4*)(s0p + lane * 4);
    float4 v1 = *(const float4*)(s1p + lane * 4);
    float c0[4] = {v0.x, v0.y, v0.z, v0.w};
    float c1[4] = {v1.x, v1.y, v1.z, v1.w};

    float tv0[8], tv1[8];
    int ti0[8], ti1[8];

#pragma unroll
    for (int r = 0; r < 8; ++r) {
        float bv = c0[0];
        int bi = lane * 4;
#pragma unroll
        for (int j = 1; j < 4; ++j)
            if (c0[j] > bv) { bv = c0[j]; bi = lane * 4 + j; }
#pragma unroll
        for (int off = 1; off < 64; off <<= 1) {
            float ov = __shfl_xor(bv, off);
            int oi = __shfl_xor(bi, off);
            if (ov > bv || (ov == bv && oi < bi)) { bv = ov; bi = oi; }
        }
        tv0[r] = bv;
        ti0[r] = bi;
        if ((bi >> 2) == lane) {
            int jj = bi & 3;
#pragma unroll
            for (int q = 0; q < 4; ++q)
                if (q == jj) c0[q] = -INFINITY;
        }
    }
#pragma unroll
    for (int r = 0; r < 8; ++r) {
        float bv = c1[0];
        int bi = lane * 4;
#pragma unroll
        for (int j = 1; j < 4; ++j)
            if (c1[j] > bv) { bv = c1[j]; bi = lane * 4 + j; }
#pragma unroll
        for (int off = 1; off < 64; off <<= 1) {
            float ov = __shfl_xor(bv, off);
            int oi = __shfl_xor(bi, off);
            if (ov > bv || (ov == bv && oi < bi)) { bv = ov; bi = oi; }
        }
        tv1[r] = bv;
        ti1[r] = bi;
        if ((bi >> 2) == lane) {
            int jj = bi & 3;
#pragma unroll
            for (int q = 0; q < 4; ++q)
                if (q == jj) c1[q] = -INFINITY;
        }
    }

    int ii = lane >> 3, jj = lane & 7;
    float a = -INFINITY, b = -INFINITY;
#pragma unroll
    for (int r = 0; r < 8; ++r) {
        if (ii == r) a = tv0[r];
        if (jj == r) b = tv1[r];
    }
    float cv = a + b;
    int cpos = lane;

    int outbase = (t * NHEAD + h) * KSEL;
#pragma unroll
    for (int r = 0; r < 8; ++r) {
        float bv = cv;
        int bp = cpos;
#pragma unroll
        for (int off = 1; off < 64; off <<= 1) {
            float ov = __shfl_xor(bv, off);
            int op = __shfl_xor(bp, off);
            if (ov > bv || (ov == bv && op < bp)) { bv = ov; bp = op; }
        }
        if (lane == 0) {
            int pi = bp >> 3, pj = bp & 7;
            int e0 = 0, e1 = 0;
#pragma unroll
            for (int q = 0; q < 8; ++q) {
                if (pi == q) e0 = ti0[q];
                if (pj == q) e1 = ti1[q];
            }
            eidx[outbase + r] = e0 * NKEY + e1;
            gates[outbase + r] = 1.0f / (1.0f + expf(-bv));
        }
        if (lane == bp) cv = -INFINITY;
    }
}

// ---------------- K5: expert gather + compute ----------------
__global__ __launch_bounds__(512, 2) void expert_k(const float* __restrict__ x,
                                                   const float* __restrict__ down,
                                                   const float* __restrict__ up,
                                                   const int* __restrict__ eidx,
                                                   const float* __restrict__ gates,
                                                   float* __restrict__ out) {
    int t = blockIdx.x;
    int w = threadIdx.x >> 6;
    int lane = threadIdx.x & 63;
    __shared__ __align__(16) float4 accs[8][256];

    const float4* x4 = (const float4*)(x + (size_t)t * HDIM);
    float4 xv[4];
#pragma unroll
    for (int j = 0; j < 4; ++j) xv[j] = x4[lane + 64 * j];

    int base = t * 64 + w * 8;
    int e[8];
    float g[8];
#pragma unroll
    for (int i = 0; i < 8; ++i) {
        e[i] = eidx[base + i];
        g[i] = gates[base + i];
    }

    float dot[8];
#pragma unroll
    for (int i = 0; i < 8; ++i) dot[i] = 0.f;
#pragma unroll
    for (int i = 0; i < 8; ++i) {
        const float4* d = (const float4*)(down + (size_t)e[i] * HDIM);
#pragma unroll
        for (int j = 0; j < 4; ++j) {
            float4 dv = d[lane + 64 * j];
            dot[i] += xv[j].x * dv.x + xv[j].y * dv.y + xv[j].z * dv.z + xv[j].w * dv.w;
        }
    }

#pragma unroll
    for (int off = 32; off >= 1; off >>= 1) {
#pragma unroll
        for (int i = 0; i < 8; ++i) dot[i] += __shfl_xor(dot[i], off);
    }
    float hm[8];
#pragma unroll
    for (int i = 0; i < 8; ++i) {
        float d = dot[i];
        hm[i] = g[i] * 0.5f * d * (1.0f + erff(d * 0.70710678118654752f));
    }

    float4 acc[4];
#pragma unroll
    for (int j = 0; j < 4; ++j) acc[j] = make_float4(0.f, 0.f, 0.f, 0.f);
#pragma unroll
    for (int i = 0; i < 8; ++i) {
        const float4* u = (const float4*)(up + (size_t)e[i] * HDIM);
        float h = hm[i];
#pragma unroll
        for (int j = 0; j < 4; ++j) {
            float4 uv = u[lane + 64 * j];
            acc[j].x = fmaf(h, uv.x, acc[j].x);
            acc[j].y = fmaf(h, uv.y, acc[j].y);
            acc[j].z = fmaf(h, uv.z, acc[j].z);
            acc[j].w = fmaf(h, uv.w, acc[j].w);
        }
    }

#pragma unroll
    for (int j = 0; j < 4; ++j) accs[w][lane + 64 * j] = acc[j];
    __syncthreads();
    if (threadIdx.x < 256) {
        int s = threadIdx.x;
        float4 o = accs[0][s];
#pragma unroll
        for (int ww = 1; ww < 8; ++ww) {
            float4 r = accs[ww][s];
            o.x += r.x; o.y += r.y; o.z += r.z; o.w += r.w;
        }
        ((float4*)(out + (size_t)t * HDIM))[s] = o;
    }
}

// ---------------- launch ----------------
extern "C" void kernel_launch(void* const* d_in, const int* in_sizes, int n_in,
                              void* d_out, int out_size, void* d_ws, size_t ws_size,
                              hipStream_t stream) {
    const float* x = (const float*)d_in[0];
    const float* gamma = (const float*)d_in[1];
    const float* beta = (const float*)d_in[2];
    const float* w_q = (const float*)d_in[3];
    const float* keys = (const float*)d_in[4];
    const float* down = (const float*)d_in[5];
    const float* up = (const float*)d_in[6];
    float* out = (float*)d_out;
    float* ws = (float*)d_ws;

    // ws layout (float offsets), total 13631488 floats = 54.5 MB (< proven 69.2 MB)
    float* psum = ws;                          // 0 .. 65536
    float* psq = ws + 65536;                   // .. 131072
    float* scale = ws + 131072;                // 1024
    float* shift = ws + 132096;                // 1024
    int* eidx = (int*)(ws + 133120);           // .. 264192
    float* gates = ws + 264192;                // .. 395264
    uint32_t* xpk = (uint32_t*)(ws + 524288);  // 2048x1024 u32   (dead after gemm0)
    uint32_t* wpk = (uint32_t*)(ws + 2621440); // 2048x1024 u32   (dead after gemm0)
    float* sim = ws + 524288;                  // 2048x4096 f32, OVERLAYS xpk+wpk
    uint32_t* kpk = (uint32_t*)(ws + 8912896); // 16x256x128 u32
    uint32_t* qpk = (uint32_t*)(ws + 9437184); // 2048x2048 u32

    bn_partial_k<<<64, 256, 0, stream>>>(x, psum, psq);
    bn_final_k<<<4, 256, 0, stream>>>(psum, psq, gamma, beta, scale, shift);

    cvt_pack_k<1><<<2048, 256, 0, stream>>>(x, xpk, scale, shift);
    cvt_pack_k<0><<<2048, 256, 0, stream>>>(w_q, wpk, nullptr, nullptr);
    cvt_keys_k<<<2048, 256, 0, stream>>>(keys, kpk);

    // q = xn @ w_q^T  (writes packed f16-pair q)
    mgemm_k<0><<<dim3(16, 16, 1), 512, 0, stream>>>(xpk, wpk, nullptr, qpk);
    // sim = q @ keys^T  per (p,h)  (fp32 out, overlays dead xpk/wpk)
    mgemm_k<1><<<dim3(16, 2, 16), 512, 0, stream>>>(qpk, kpk, sim, nullptr);

    topk_k<<<2048, 512, 0, stream>>>(sim, eidx, gates);
    expert_k<<<2048, 512, 0, stream>>>(x, down, up, eidx, gates, out);
}